// Round 6
// baseline (132.451 us; speedup 1.0000x reference)
//
#include <hip/hip_runtime.h>
#include <stdint.h>

#define NS 65536      // B*H*W samples
#define D 64          // embed dim
#define K 1024        // codebook size
#define NEL 4194304   // NS*D
#define MARGIN_KEY 0.025f  // key units (= half dist units); approx+pack err ~1e-3

typedef short bf16x8 __attribute__((ext_vector_type(8)));
typedef float f32x4 __attribute__((ext_vector_type(4)));
typedef float f32x16 __attribute__((ext_vector_type(16)));

static __device__ __forceinline__ unsigned short bf16_rne(float x) {
    union { float f; uint32_t u; } v; v.f = x;
    uint32_t r = v.u + 0x7FFFu + ((v.u >> 16) & 1u);
    return (unsigned short)(r >> 16);
}
static __device__ __forceinline__ float bf16f(unsigned short h) {
    union { uint32_t u; float f; } v; v.u = ((uint32_t)h) << 16;
    return v.f;
}

// ---------------------------------------------------------------------------
// Prep: split codebook into bf16 hi/lo packed for the 32x32x16 MFMA:
//   P[tile t(32 codes)][f: 0-3 = hi slice s, 4-7 = lo slice s][lane][8 shorts]
//   lane = kh*32 + code (kh = k-half of the 16-K slice), elems = dims
//   s*16 + kh*8 .. +8.  Per tile = 8 KB contiguous (glds/ds_read linear).
// Also ||m_k||^2 fp32, zero loss acc + completion counter.
// ---------------------------------------------------------------------------
__global__ __launch_bounds__(256) void vq_prep(
    const float* __restrict__ cm,        // [D,K]
    unsigned short* __restrict__ P,      // packed frags, 256 KB
    float* __restrict__ cnorm,           // [K]
    double* __restrict__ acc,
    unsigned int* __restrict__ cnt)
{
    const int tx = threadIdx.x;
    const int c  = tx & 31;              // code within tile
    const int dg = tx >> 5;              // dim group 0..7 (8 dims each)
    const int t  = blockIdx.x;           // tile 0..31
    const int k  = t * 32 + c;
    if (t == 0 && tx == 0) { *acc = 0.0; *cnt = 0u; }

    float p = 0.f;
    bf16x8 hv, lv;
#pragma unroll
    for (int j = 0; j < 8; ++j) {
        float v = cm[(dg * 8 + j) * K + k];   // coalesced over c
        unsigned short hb = bf16_rne(v);
        hv[j] = (short)hb;
        lv[j] = (short)bf16_rne(v - bf16f(hb));
        p = fmaf(v, v, p);
    }
    const int s = dg >> 1, kh = dg & 1;
    *(bf16x8*)(P + ((size_t)(t * 8 + s) * 64 + kh * 32 + c) * 8)     = hv;
    *(bf16x8*)(P + ((size_t)(t * 8 + 4 + s) * 64 + kh * 32 + c) * 8) = lv;

    __shared__ float pn[32][9];
    pn[c][dg] = p;
    __syncthreads();
    if (tx < 32) {
        float sm = 0.f;
#pragma unroll
        for (int g = 0; g < 8; ++g) sm += pn[tx][g];
        cnorm[t * 32 + tx] = sm;
    }
}

// ---------------------------------------------------------------------------
// Main: 32x32x16 MFMA distance loop -- HALF the iterations of rounds 2-5
// (32 tiles of 32 codes), which all hit the same 57us wall regardless of
// sync structure (per-iteration exposed latency binds, not pipes).
// 512 blocks x 256 thr (4 waves); wave w owns samples w*32..+32. Per tile:
// 8x ds_read_b128 B-frags, single 12-MFMA chain (hi.hi, hi.lo, lo.hi over
// 4 K-slices), key = ||m||^2/2 - dot, packed-index top-2 (tile idx in low
// 6 mantissa bits). Ring: 4 x 8 KB, 2 glds/thread/tile, counted vmcnt(4)
// + raw barrier (never vmcnt(0) in-loop). C/D layout (m74/m101):
// col=lane&31, row=(reg&3)+8*(reg>>2)+4*(lane>>5).
// Finalize (loss write) fused via device-scope counter: saves a launch
// (~60us fixed non-main time per round, one launch of it deletable).
// ---------------------------------------------------------------------------
__global__ __launch_bounds__(256, 2) void vq_main(
    const float* __restrict__ xin,           // [NS,D]
    const float* __restrict__ cm,            // [D,K] (exact rescore)
    const unsigned short* __restrict__ P,    // packed frags
    const float* __restrict__ cnorm,         // [K]
    float* __restrict__ outq,                // [NS,D]
    float* __restrict__ outidx,              // [NS]
    double* __restrict__ acc_g,
    unsigned int* __restrict__ cnt_g,
    float* __restrict__ loss_out)
{
    // smemA phase1: xh[128][72] + xl[128][72] (36864 B) bf16 hi/lo of x
    // smemA phase2 (alias): mb1/mb2 f32[128][33] (2 x 16896 B)
    // smemA phase3 (alias): red f32[256]
    __shared__ char smemA[36864];
    __shared__ unsigned short ring[4][4096];    // 4-deep ring of 8 KB B tiles
    __shared__ float cn_lds[1024];              // ||m||^2 / 2
    __shared__ int   widx[128];

    unsigned short* xh = (unsigned short*)smemA;            // stride 72
    unsigned short* xl = (unsigned short*)(smemA + 18432);
    float* mb1 = (float*)smemA;                 // [128][33]
    float* mb2 = (float*)(smemA + 16896);
    float* red = (float*)smemA;

    const int tx = threadIdx.x;
    const int S0 = blockIdx.x * 128;
    const int w = tx >> 6, l = tx & 63;

#define ISSUE(T) do {                                                          \
        const unsigned short* g_ = P + (size_t)(T) * 4096 + tx * 8;            \
        __builtin_amdgcn_global_load_lds(g_, &ring[(T) & 3][tx * 8], 16, 0, 0);\
        __builtin_amdgcn_global_load_lds(g_ + 2048, &ring[(T) & 3][2048 + tx * 8], 16, 0, 0); \
    } while (0)
#define WAITV(N) asm volatile("s_waitcnt vmcnt(" #N ")" ::: "memory")

    // prologue: stage tiles 0..2 (drained by the staging __syncthreads)
    ISSUE(0); ISSUE(1); ISSUE(2);

    // ---- stage x -> bf16 hi/lo in LDS (one-time) ----
    {
        const int sr = tx >> 1, dh = (tx & 1) * 32;
        const float* gp = xin + (size_t)(S0 + sr) * D + dh;
#pragma unroll
        for (int g = 0; g < 2; ++g) {
            bf16x8 hv0, hv1, lv0, lv1;
#pragma unroll
            for (int j = 0; j < 8; ++j) {
                float va = gp[g * 16 + j], vb = gp[g * 16 + 8 + j];
                unsigned short ha = bf16_rne(va), hb = bf16_rne(vb);
                hv0[j] = (short)ha; hv1[j] = (short)hb;
                lv0[j] = (short)bf16_rne(va - bf16f(ha));
                lv1[j] = (short)bf16_rne(vb - bf16f(hb));
            }
            *(bf16x8*)(xh + sr * 72 + dh + g * 16)     = hv0;
            *(bf16x8*)(xh + sr * 72 + dh + g * 16 + 8) = hv1;
            *(bf16x8*)(xl + sr * 72 + dh + g * 16)     = lv0;
            *(bf16x8*)(xl + sr * 72 + dh + g * 16 + 8) = lv1;
        }
#pragma unroll
        for (int q = 0; q < 4; ++q)
            cn_lds[q * 256 + tx] = 0.5f * cnorm[q * 256 + tx];
    }
    __syncthreads();   // drains x loads AND tiles 0-2 (full drain, once)

    // loop-invariant A fragments: row = w*32 + (l&31), k-half = l>>5
    const int arow = w * 32 + (l & 31);
    const int kh8 = (l >> 5) * 8;
    bf16x8 AH0 = *(const bf16x8*)(xh + arow * 72 + 0  + kh8);
    bf16x8 AH1 = *(const bf16x8*)(xh + arow * 72 + 16 + kh8);
    bf16x8 AH2 = *(const bf16x8*)(xh + arow * 72 + 32 + kh8);
    bf16x8 AH3 = *(const bf16x8*)(xh + arow * 72 + 48 + kh8);
    bf16x8 AL0 = *(const bf16x8*)(xl + arow * 72 + 0  + kh8);
    bf16x8 AL1 = *(const bf16x8*)(xl + arow * 72 + 16 + kh8);
    bf16x8 AL2 = *(const bf16x8*)(xl + arow * 72 + 32 + kh8);
    bf16x8 AL3 = *(const bf16x8*)(xl + arow * 72 + 48 + kh8);

    // top-2 of key = cn/2 - dot, tile idx packed in low 6 mantissa bits
    float b1[16], b2[16];
#pragma unroll
    for (int j = 0; j < 16; ++j) { b1[j] = 3.4e38f; b2[j] = 3.4e38f; }

    const f32x16 Z16 = {0.f,0.f,0.f,0.f,0.f,0.f,0.f,0.f,
                        0.f,0.f,0.f,0.f,0.f,0.f,0.f,0.f};

#define BODY(T) do {                                                           \
        const unsigned short* bt_ = &ring[(T) & 3][0];                         \
        bf16x8 Bh0 = *(const bf16x8*)(bt_ + 0    + l * 8);                     \
        bf16x8 Bh1 = *(const bf16x8*)(bt_ + 512  + l * 8);                     \
        bf16x8 Bh2 = *(const bf16x8*)(bt_ + 1024 + l * 8);                     \
        bf16x8 Bh3 = *(const bf16x8*)(bt_ + 1536 + l * 8);                     \
        bf16x8 Bl0 = *(const bf16x8*)(bt_ + 2048 + l * 8);                     \
        bf16x8 Bl1 = *(const bf16x8*)(bt_ + 2560 + l * 8);                     \
        bf16x8 Bl2 = *(const bf16x8*)(bt_ + 3072 + l * 8);                     \
        bf16x8 Bl3 = *(const bf16x8*)(bt_ + 3584 + l * 8);                     \
        f32x16 a_ = Z16;                                                       \
        a_ = __builtin_amdgcn_mfma_f32_32x32x16_bf16(AH0, Bh0, a_, 0, 0, 0);   \
        a_ = __builtin_amdgcn_mfma_f32_32x32x16_bf16(AH1, Bh1, a_, 0, 0, 0);   \
        a_ = __builtin_amdgcn_mfma_f32_32x32x16_bf16(AH2, Bh2, a_, 0, 0, 0);   \
        a_ = __builtin_amdgcn_mfma_f32_32x32x16_bf16(AH3, Bh3, a_, 0, 0, 0);   \
        a_ = __builtin_amdgcn_mfma_f32_32x32x16_bf16(AH0, Bl0, a_, 0, 0, 0);   \
        a_ = __builtin_amdgcn_mfma_f32_32x32x16_bf16(AH1, Bl1, a_, 0, 0, 0);   \
        a_ = __builtin_amdgcn_mfma_f32_32x32x16_bf16(AH2, Bl2, a_, 0, 0, 0);   \
        a_ = __builtin_amdgcn_mfma_f32_32x32x16_bf16(AH3, Bl3, a_, 0, 0, 0);   \
        a_ = __builtin_amdgcn_mfma_f32_32x32x16_bf16(AL0, Bh0, a_, 0, 0, 0);   \
        a_ = __builtin_amdgcn_mfma_f32_32x32x16_bf16(AL1, Bh1, a_, 0, 0, 0);   \
        a_ = __builtin_amdgcn_mfma_f32_32x32x16_bf16(AL2, Bh2, a_, 0, 0, 0);   \
        a_ = __builtin_amdgcn_mfma_f32_32x32x16_bf16(AL3, Bh3, a_, 0, 0, 0);   \
        const float ch_ = cn_lds[(T) * 32 + (l & 31)];                         \
        const unsigned tt_ = (unsigned)(T);                                    \
        _Pragma("unroll")                                                      \
        for (int j = 0; j < 16; ++j) {                                         \
            float k_ = ch_ - a_[j];                                            \
            unsigned pu_ = (__builtin_bit_cast(unsigned, k_) & 0xFFFFFFC0u) | tt_; \
            float f_ = __builtin_bit_cast(float, pu_);                         \
            b2[j] = __builtin_amdgcn_fmed3f(b1[j], f_, b2[j]);                 \
            b1[j] = fminf(b1[j], f_);                                          \
        }                                                                      \
    } while (0)

    for (int t = 0; t < 29; ++t) {
        WAITV(4);                         // 2 loads/tile: oldest tile landed
        __builtin_amdgcn_s_barrier();     // all threads' shares landed
        ISSUE(t + 3);                     // buf[(t-1)&3]: consumed last iter
        BODY(t);
    }
    WAITV(4); __builtin_amdgcn_s_barrier(); BODY(29);
    WAITV(2); __builtin_amdgcn_s_barrier(); BODY(30);
    WAITV(0); __builtin_amdgcn_s_barrier(); BODY(31);

    // ---- merge: scatter per-lane top-2 into sample-major [128][33] ----
    // write banks (row + c) % 32: 2-way (free); read banks (tx + c): clean.
    {
        const int cc = l & 31, hh = l >> 5;
#pragma unroll
        for (int j = 0; j < 16; ++j) {
            const int r = (j & 3) + 8 * (j >> 2) + 4 * hh;   // C/D row
            const int sr2 = w * 32 + r;
            mb1[sr2 * 33 + cc] = b1[j];
            mb2[sr2 * 33 + cc] = b2[j];
        }
    }
    __syncthreads();

    if (tx < 128) {   // thread tx owns local sample tx
        float B1 = 3.4e38f, B2 = 3.4e38f; int I1 = 0, I2 = 0;
#pragma unroll
        for (int c = 0; c < 32; ++c) {
            float v1 = mb1[tx * 33 + c];
            float v2 = mb2[tx * 33 + c];
            int j1 = (int)(__builtin_bit_cast(unsigned, v1) & 63u) * 32 + c;
            int j2 = (int)(__builtin_bit_cast(unsigned, v2) & 63u) * 32 + c;
            if (v1 < B1)      { B2 = B1; I2 = I1; B1 = v1; I1 = j1; }
            else if (v1 < B2) { B2 = v1; I2 = j1; }
            if (v2 < B1)      { B2 = B1; I2 = I1; B1 = v2; I1 = j2; }
            else if (v2 < B2) { B2 = v2; I2 = j2; }
        }
        int winner = I1;
        if (B2 - B1 < MARGIN_KEY) {
            // exact fp32 rescore of both candidates (key = cn/2 - dot)
            const float* xp = xin + (size_t)(S0 + tx) * D;
            float a0 = 0, a1 = 0, a2 = 0, a3 = 0, e0 = 0, e1 = 0, e2 = 0, e3 = 0;
            for (int dd = 0; dd < D; dd += 4) {
                float x0 = xp[dd], x1 = xp[dd + 1], x2 = xp[dd + 2], x3 = xp[dd + 3];
                a0 = fmaf(x0, cm[(dd + 0) * K + I1], a0);
                a1 = fmaf(x1, cm[(dd + 1) * K + I1], a1);
                a2 = fmaf(x2, cm[(dd + 2) * K + I1], a2);
                a3 = fmaf(x3, cm[(dd + 3) * K + I1], a3);
                e0 = fmaf(x0, cm[(dd + 0) * K + I2], e0);
                e1 = fmaf(x1, cm[(dd + 1) * K + I2], e1);
                e2 = fmaf(x2, cm[(dd + 2) * K + I2], e2);
                e3 = fmaf(x3, cm[(dd + 3) * K + I2], e3);
            }
            float d1 = cn_lds[I1] - ((a0 + a1) + (a2 + a3));
            float d2 = cn_lds[I2] - ((e0 + e1) + (e2 + e3));
            if (d2 < d1 || (d2 == d1 && I2 < I1)) winner = I2;
        }
        widx[tx] = winner;
    }
    __syncthreads();

    // ---- gather (hi+lo reconstruct from packed P) + STE + loss partial ----
    float psum = 0.f;
#pragma unroll
    for (int half = 0; half < 2; ++half) {
        const int sl = (tx >> 2) + half * 64, d0 = (tx & 3) * 16;
        const int gs = S0 + sl;
        const int wi = widx[sl];
        const int gt = wi >> 5, gc = wi & 31;
        const int s4 = d0 >> 4;              // K-slice 0..3
        const unsigned short* gh = P + ((size_t)(gt * 8 + s4) * 64 + gc) * 8;
        const unsigned short* gl = P + ((size_t)(gt * 8 + 4 + s4) * 64 + gc) * 8;
        bf16x8 h0 = *(const bf16x8*)(gh);          // dims d0..d0+8 (kh=0)
        bf16x8 h1 = *(const bf16x8*)(gh + 256);    // dims d0+8..d0+16 (kh=1)
        bf16x8 l0 = *(const bf16x8*)(gl);
        bf16x8 l1 = *(const bf16x8*)(gl + 256);
        const float* xr = xin + (size_t)gs * D + d0;
        float* oq = outq + (size_t)gs * D + d0;
#pragma unroll
        for (int g = 0; g < 4; ++g) {
            float4 xv = *(const float4*)(xr + 4 * g);
            float q0 = bf16f((unsigned short)(g < 2 ? h0[4 * g + 0] : h1[4 * g - 8 + 0])) +
                       bf16f((unsigned short)(g < 2 ? l0[4 * g + 0] : l1[4 * g - 8 + 0]));
            float q1 = bf16f((unsigned short)(g < 2 ? h0[4 * g + 1] : h1[4 * g - 8 + 1])) +
                       bf16f((unsigned short)(g < 2 ? l0[4 * g + 1] : l1[4 * g - 8 + 1]));
            float q2 = bf16f((unsigned short)(g < 2 ? h0[4 * g + 2] : h1[4 * g - 8 + 2])) +
                       bf16f((unsigned short)(g < 2 ? l0[4 * g + 2] : l1[4 * g - 8 + 2]));
            float q3 = bf16f((unsigned short)(g < 2 ? h0[4 * g + 3] : h1[4 * g - 8 + 3])) +
                       bf16f((unsigned short)(g < 2 ? l0[4 * g + 3] : l1[4 * g - 8 + 3]));
            float dx = q0 - xv.x, dy = q1 - xv.y, dz = q2 - xv.z, dw = q3 - xv.w;
            float4 o;
            o.x = xv.x + dx; o.y = xv.y + dy; o.z = xv.z + dz; o.w = xv.w + dw;
            *(float4*)(oq + 4 * g) = o;
            psum = fmaf(dx, dx, psum);
            psum = fmaf(dy, dy, psum);
            psum = fmaf(dz, dz, psum);
            psum = fmaf(dw, dw, psum);
        }
    }

    if (tx < 128)
        outidx[S0 + tx] = (float)widx[tx];

    __syncthreads();   // merge arrays dead; red aliases
    red[tx] = psum;
    __syncthreads();
    for (int st = 128; st > 0; st >>= 1) {
        if (tx < st) red[tx] += red[tx + st];
        __syncthreads();
    }
    if (tx == 0) {
        atomicAdd(acc_g, (double)red[0]);
        __threadfence();
        unsigned prev = atomicAdd(cnt_g, 1u);
        if (prev == gridDim.x - 1) {          // last block: fused finalize
            __threadfence();
            double a = atomicAdd(acc_g, 0.0); // device-scope read of total
            float m = (float)(a / (double)NEL);
            *loss_out = m + 0.25f * m;
        }
    }
#undef ISSUE
#undef WAITV
#undef BODY
}

extern "C" void kernel_launch(void* const* d_in, const int* in_sizes, int n_in,
                              void* d_out, int out_size, void* d_ws, size_t ws_size,
                              hipStream_t stream) {
    const float* xin = (const float*)d_in[0];   // [16,64,64,64] fp32
    const float* cm  = (const float*)d_in[1];   // [64,1024] fp32

    float* out     = (float*)d_out;
    float* outq    = out;                 // 4194304 floats
    float* outidx  = out + NEL;           // 65536 floats (indices)
    float* outloss = out + NEL + NS;      // 1 float

    // workspace: packed P 256 KB | cnorm 4 KB | acc 8 B | cnt 4 B
    unsigned short* P = (unsigned short*)d_ws;
    float*  cnorm = (float*)((char*)d_ws + 262144);
    double* acc   = (double*)((char*)d_ws + 266240);
    unsigned int* cnt = (unsigned int*)((char*)d_ws + 266248);

    vq_prep<<<32, 256, 0, stream>>>(cm, P, cnorm, acc, cnt);
    vq_main<<<512, 256, 0, stream>>>(xin, cm, P, cnorm, outq, outidx,
                                     acc, cnt, outloss);
}